// Round 10
// baseline (381.411 us; speedup 1.0000x reference)
//
#include <hip/hip_runtime.h>

#define D 64

// --- degree histogram over dst, dst-sliced for XCD-local atomics -----------
__global__ void count_deg_sliced_kernel(const int* __restrict__ dst, int* __restrict__ deg,
                                        int nE, int slice_size) {
    const int g  = blockIdx.x & 7;    // slice id == XCD id (perf heuristic)
    const int gb = blockIdx.x >> 3;
    const int lo = g * slice_size;
    const int hi = lo + slice_size;
    int e4 = (gb * 256 + (int)threadIdx.x) * 4;
    if (e4 + 3 < nE) {
        int4 d = *(const int4*)(dst + e4);
        if (d.x >= lo && d.x < hi) atomicAdd(&deg[d.x], 1);
        if (d.y >= lo && d.y < hi) atomicAdd(&deg[d.y], 1);
        if (d.z >= lo && d.z < hi) atomicAdd(&deg[d.z], 1);
        if (d.w >= lo && d.w < hi) atomicAdd(&deg[d.w], 1);
    } else if (e4 < nE) {
        for (int e = e4; e < nE; ++e) {
            int dd = dst[e];
            if (dd >= lo && dd < hi) atomicAdd(&deg[dd], 1);
        }
    }
}

// --- hierarchical exclusive scan: A (per-block tile scan) ------------------
__global__ __launch_bounds__(256) void scan_a_kernel(const int* __restrict__ deg,
                                                     int* __restrict__ row_ptr,
                                                     int* __restrict__ blocksums, int N) {
    __shared__ int s[256];
    int t = threadIdx.x;
    int i = blockIdx.x * 256 + t;
    int v = (i < N) ? deg[i] : 0;
    s[t] = v;
    __syncthreads();
    #pragma unroll
    for (int d = 1; d < 256; d <<= 1) {
        int u = (t >= d) ? s[t - d] : 0;
        __syncthreads();
        s[t] += u;
        __syncthreads();
    }
    if (i < N) row_ptr[i] = s[t] - v;             // exclusive (block-local)
    if (t == 255) blocksums[blockIdx.x] = s[255]; // block total
}

// --- B: single-block exclusive scan of block sums (nb <= 256) --------------
__global__ __launch_bounds__(256) void scan_b_kernel(int* __restrict__ blocksums,
                                                     int* __restrict__ row_ptr,
                                                     int nb, int N) {
    __shared__ int s[256];
    int t = threadIdx.x;
    int v = (t < nb) ? blocksums[t] : 0;
    s[t] = v;
    __syncthreads();
    #pragma unroll
    for (int d = 1; d < 256; d <<= 1) {
        int u = (t >= d) ? s[t - d] : 0;
        __syncthreads();
        s[t] += u;
        __syncthreads();
    }
    if (t < nb) blocksums[t] = s[t] - v;  // exclusive block offsets
    if (t == 255) row_ptr[N] = s[255];    // total = E
}

// --- C: apply block offsets, emit final row_ptr + cursor -------------------
__global__ __launch_bounds__(256) void scan_c_kernel(int* __restrict__ row_ptr,
                                                     int* __restrict__ cursor,
                                                     const int* __restrict__ blocksums, int N) {
    int i = blockIdx.x * 256 + threadIdx.x;
    if (i < N) {
        int r = row_ptr[i] + blocksums[blockIdx.x];
        row_ptr[i] = r;
        cursor[i] = r;
    }
}

// --- bucket edges by dst: col[pos] = src, dst-sliced for XCD locality ------
__global__ __launch_bounds__(256) void fill_csr_sliced_kernel(
    const int* __restrict__ src, const int* __restrict__ dst,
    int* __restrict__ cursor, int* __restrict__ col,
    int nE, int slice_size)
{
    const int g  = blockIdx.x & 7;
    const int gb = blockIdx.x >> 3;
    const int lo = g * slice_size;
    const int hi = lo + slice_size;
    int e4 = (gb * 256 + (int)threadIdx.x) * 4;
    if (e4 + 3 < nE) {
        int4 d = *(const int4*)(dst + e4);
        bool m0 = (d.x >= lo) & (d.x < hi);
        bool m1 = (d.y >= lo) & (d.y < hi);
        bool m2 = (d.z >= lo) & (d.z < hi);
        bool m3 = (d.w >= lo) & (d.w < hi);
        if (m0 | m1 | m2 | m3) {
            int4 s = *(const int4*)(src + e4);
            if (m0) col[atomicAdd(&cursor[d.x], 1)] = s.x;
            if (m1) col[atomicAdd(&cursor[d.y], 1)] = s.y;
            if (m2) col[atomicAdd(&cursor[d.z], 1)] = s.z;
            if (m3) col[atomicAdd(&cursor[d.w], 1)] = s.w;
        }
    } else if (e4 < nE) {
        for (int e = e4; e < nE; ++e) {
            int dd = dst[e];
            if (dd >= lo && dd < hi) col[atomicAdd(&cursor[dd], 1)] = src[e];
        }
    }
}

// --- transpose row-major [N][64] -> chunked [4][N][16] ---------------------
__global__ __launch_bounds__(256) void to_chunked_kernel(const float4* __restrict__ x4,
                                                         float4* __restrict__ xc4, int N) {
    int tid = blockIdx.x * 256 + threadIdx.x;   // over N*16 float4s
    int n16 = N * 16;
    if (tid < n16) {
        int n4 = N * 4;
        int c = tid / n4;
        int r = tid - c * n4;
        int i = r >> 2, q = r & 3;
        xc4[tid] = x4[i * 16 + c * 4 + q];
    }
}

// --- phase 1: gather on chunked slab, 16 edge-slots x 4 float4-lanes -------
// ONE wave per (node, chunk). Lane es=lane>>2 handles edge e0+es, loading its
// index directly (col[e0+es], 16 consecutive dwords, dup x4 -> 1 transaction)
// -> zero bpermute. One dwordx4 load covers 16 edges (1KB/wave). Tail edges
// masked (cndmask), no pad-correction loads. Reduce = 4 shfl_xor rounds.
__global__ __launch_bounds__(256) void sage_gather_kernel(
    const float* __restrict__ hc, const int* __restrict__ row_ptr,
    const int* __restrict__ col, float* __restrict__ tc, int N)
{
    const int g     = blockIdx.x & 7;
    const int chunk = g & 3;
    const int half  = g >> 2;
    const int gb    = blockIdx.x >> 3;
    const int lane  = threadIdx.x & 63;
    const int es    = lane >> 2;      // edge slot 0..15
    const int q     = lane & 3;       // float4 quad within 16-float row
    const int w     = threadIdx.x >> 6;

    const float4* __restrict__ slab = (const float4*)(hc + (size_t)chunk * N * 16);
    float4* __restrict__ tslab      = (float4*)(tc + (size_t)chunk * N * 16);

    const int Nh = (N + 1) >> 1;
    const int lo = half * Nh;
    const int hi = (lo + Nh < N) ? (lo + Nh) : N;

    int i0 = lo + gb * 4 + w;
    if (i0 >= hi) return;
    const int i  = __builtin_amdgcn_readfirstlane(i0);
    const int rs = __builtin_amdgcn_readfirstlane(row_ptr[i]);
    const int re = __builtin_amdgcn_readfirstlane(row_ptr[i + 1]);
    const int deg = re - rs;

    float4 self = slab[(size_t)i * 4 + q];   // independent; issues early

    float4 acc0 = {0,0,0,0}, acc1 = {0,0,0,0};
    int e0 = rs;
    // full pairs (both 16-blocks unmasked, two loads in flight)
    while (re - e0 >= 32) {
        int ia = col[e0 + es];
        int ib = col[e0 + 16 + es];
        float4 va = slab[(size_t)ia * 4 + q];
        float4 vb = slab[(size_t)ib * 4 + q];
        acc0.x += va.x; acc0.y += va.y; acc0.z += va.z; acc0.w += va.w;
        acc1.x += vb.x; acc1.y += vb.y; acc1.z += vb.z; acc1.w += vb.w;
        e0 += 32;
    }
    int rem = re - e0;               // 0..31, scalar
    if (rem > 0) {
        int ea = e0 + es;
        int idx = col[(ea < re) ? ea : (re - 1)];
        float4 v = slab[(size_t)idx * 4 + q];
        bool val = (ea < re);
        acc0.x += val ? v.x : 0.0f; acc0.y += val ? v.y : 0.0f;
        acc0.z += val ? v.z : 0.0f; acc0.w += val ? v.w : 0.0f;
    }
    if (rem > 16) {
        int ea = e0 + 16 + es;
        int idx = col[(ea < re) ? ea : (re - 1)];
        float4 v = slab[(size_t)idx * 4 + q];
        bool val = (ea < re);
        acc1.x += val ? v.x : 0.0f; acc1.y += val ? v.y : 0.0f;
        acc1.z += val ? v.z : 0.0f; acc1.w += val ? v.w : 0.0f;
    }

    float4 acc;
    acc.x = acc0.x + acc1.x; acc.y = acc0.y + acc1.y;
    acc.z = acc0.z + acc1.z; acc.w = acc0.w + acc1.w;
    #pragma unroll
    for (int m = 4; m <= 32; m <<= 1) {
        acc.x += __shfl_xor(acc.x, m);
        acc.y += __shfl_xor(acc.y, m);
        acc.z += __shfl_xor(acc.z, m);
        acc.w += __shfl_xor(acc.w, m);
    }
    float invd = 1.0f / (float)(deg + 1);
    float4 tv;
    tv.x = (acc.x + self.x) * invd;
    tv.y = (acc.y + self.y) * invd;
    tv.z = (acc.z + self.z) * invd;
    tv.w = (acc.w + self.w) * invd;
    if (es == 0) tslab[(size_t)i * 4 + q] = tv;   // 4 lanes, one 64B line
}

// --- phase 2: dense MLP out = relu?(t @ W + b), chunked t input ------------
// One wave per node. Feature k lives on lane ((k>>4)<<2)|((k>>2)&3),
// component k&3 (chunked layout). 4 independent FMA chains (k-split).
__global__ __launch_bounds__(256) void sage_mlp_kernel(
    const float* __restrict__ t, const float* __restrict__ W,
    const float* __restrict__ bias, float* __restrict__ out,
    int N, int do_relu, int out_chunked)
{
    __shared__ float Ws[D * D];
    for (int idx = threadIdx.x; idx < D * D; idx += 256) Ws[idx] = W[idx];
    const int lane = threadIdx.x & 63;
    const int w    = threadIdx.x >> 6;
    const float bj = bias[lane];
    __syncthreads();

    const int l16 = lane & 15;
    const size_t roff = (size_t)(l16 >> 2) * ((size_t)N * 4) + (l16 & 3);
    const float4* __restrict__ t4 = (const float4*)t;
    const size_t coff = (size_t)(lane >> 4) * ((size_t)N * 16) + (lane & 15);

    int i0 = blockIdx.x * 4 + w;
    if (i0 >= N) return;
    const int i = __builtin_amdgcn_readfirstlane(i0);
    float4 tv = t4[roff + (size_t)i * 4];

    float o0 = bj, o1 = 0.0f, o2 = 0.0f, o3 = 0.0f;
    #pragma unroll
    for (int k = 0; k < 16; ++k) {
        #define BC(kk) __int_as_float(__builtin_amdgcn_readlane(__float_as_int( \
            (((kk) & 3) == 0) ? tv.x : (((kk) & 3) == 1) ? tv.y :               \
            (((kk) & 3) == 2) ? tv.z : tv.w), (((kk) >> 4) << 2) | (((kk) >> 2) & 3)))
        o0 = fmaf(BC(k),      Ws[(k)      * D + lane], o0);
        o1 = fmaf(BC(k + 16), Ws[(k + 16) * D + lane], o1);
        o2 = fmaf(BC(k + 32), Ws[(k + 32) * D + lane], o2);
        o3 = fmaf(BC(k + 48), Ws[(k + 48) * D + lane], o3);
        #undef BC
    }
    float o = (o0 + o1) + (o2 + o3);
    if (do_relu) o = fmaxf(o, 0.0f);
    if (out_chunked) out[coff + (size_t)i * 16] = o;
    else             out[(size_t)i * D + lane] = o;
}

extern "C" void kernel_launch(void* const* d_in, const int* in_sizes, int n_in,
                              void* d_out, int out_size, void* d_ws, size_t ws_size,
                              hipStream_t stream) {
    const float* x   = (const float*)d_in[0];
    const int*   src = (const int*)d_in[1];
    const int*   dst = (const int*)d_in[2];
    const float* W0  = (const float*)d_in[3];
    const float* b0  = (const float*)d_in[4];
    const float* W1  = (const float*)d_in[5];
    const float* b1  = (const float*)d_in[6];
    const float* W2  = (const float*)d_in[7];
    const float* b2  = (const float*)d_in[8];
    float* out = (float*)d_out;

    const int N = in_sizes[0] / D;   // 50000
    const int E = in_sizes[1];       // 800000

    const int scan_blocks = (N + 255) / 256;  // 196 (<= 256 required by scan_b)

    // workspace: deg | row_ptr | cursor | blocksums | col | A | B | tc
    // A = xc and later h2c (xc dead after first gather); B = h1c.
    char* ws = (char*)d_ws;
    size_t off = 0;
    auto alloc = [&](size_t bytes) -> void* {
        void* p = ws + off;
        off = (off + bytes + 255) & ~(size_t)255;
        return p;
    };
    int*   deg       = (int*)  alloc((size_t)N * sizeof(int));
    int*   row_ptr   = (int*)  alloc((size_t)(N + 1) * sizeof(int));
    int*   cursor    = (int*)  alloc((size_t)N * sizeof(int));
    int*   blocksums = (int*)  alloc((size_t)scan_blocks * sizeof(int));
    int*   col       = (int*)  alloc((size_t)E * sizeof(int));
    float* A         = (float*)alloc((size_t)N * D * sizeof(float));
    float* B         = (float*)alloc((size_t)N * D * sizeof(float));
    float* tc        = (float*)alloc((size_t)N * D * sizeof(float));

    // --- build CSR (once per call; reused by all 3 layers) ---
    hipMemsetAsync(deg, 0, (size_t)N * sizeof(int), stream);
    const int e4_blocks = (E / 4 + 255) / 256;  // 782
    const int slice_size = (N + 7) / 8;         // 6250
    count_deg_sliced_kernel<<<e4_blocks * 8, 256, 0, stream>>>(dst, deg, E, slice_size);
    scan_a_kernel<<<scan_blocks, 256, 0, stream>>>(deg, row_ptr, blocksums, N);
    scan_b_kernel<<<1, 256, 0, stream>>>(blocksums, row_ptr, scan_blocks, N);
    scan_c_kernel<<<scan_blocks, 256, 0, stream>>>(row_ptr, cursor, blocksums, N);
    fill_csr_sliced_kernel<<<e4_blocks * 8, 256, 0, stream>>>(src, dst, cursor, col, E, slice_size);

    // --- transpose x into chunked layout ---
    const int tr_blocks = (N * 16 + 255) / 256;  // 3125
    to_chunked_kernel<<<tr_blocks, 256, 0, stream>>>((const float4*)x, (float4*)A, N);

    // one (node,chunk) task per wave: 8 groups x ceil(Nh/4) blocks
    const int Nh = (N + 1) >> 1;                    // 25000
    const int gather_blocks = 8 * ((Nh + 3) / 4);   // 50000
    const int mlp_blocks    = (N + 3) / 4;          // 12500

    // layer 0: A(xc) -> tc -> B(h1c, chunked)
    sage_gather_kernel<<<gather_blocks, 256, 0, stream>>>(A, row_ptr, col, tc, N);
    sage_mlp_kernel<<<mlp_blocks, 256, 0, stream>>>(tc, W0, b0, B, N, 1, 1);

    // layer 1: B -> tc -> A(h2c, chunked; overwrites dead xc)
    sage_gather_kernel<<<gather_blocks, 256, 0, stream>>>(B, row_ptr, col, tc, N);
    sage_mlp_kernel<<<mlp_blocks, 256, 0, stream>>>(tc, W1, b1, A, N, 1, 1);

    // layer 2: A -> tc -> out (row-major)
    sage_gather_kernel<<<gather_blocks, 256, 0, stream>>>(A, row_ptr, col, tc, N);
    sage_mlp_kernel<<<mlp_blocks, 256, 0, stream>>>(tc, W2, b2, out, N, 0, 0);
}